// Round 8
// baseline (532.297 us; speedup 1.0000x reference)
//
#include <hip/hip_runtime.h>

#define D 128
#define CSR_STRIDE 64     // in-deg ~ Poisson(16); P(>64) ~ 0, guarded anyway
#define NCH 64            // edge chunks for binned histogram / fill
#define NR  8             // node ranges: 12500 nodes packed 2-per-int = 25 KB LDS

typedef short bh8 __attribute__((ext_vector_type(8)));
typedef float f32x4 __attribute__((ext_vector_type(4)));

__device__ __forceinline__ unsigned short f2b(float f) {
    unsigned u = __float_as_uint(f);
    u += 0x7fffu + ((u >> 16) & 1u);          // RNE
    return (unsigned short)(u >> 16);
}
__device__ __forceinline__ float b2f(unsigned short h) {
    return __uint_as_float(((unsigned)h) << 16);
}

// ------------------------------------------------------------ MFMA GEMM
// (R5-proven config: ~46 us/dispatch.) C = A @ W, 128x128 tile, 4 waves.
// A staged via 32 KB swizzled LDS; B fragments PERSISTENT in registers
// (per-k-step global B regressed to ~78 us in R6 — MFMA stalls on L2
// latency; do not repeat).
// AMODE: 0 bf16 A; 1 bf16 A + relu(scale*a+shift); 2 fp32 A
// EMODE: 0 o=acc+b; 1 o=acc*rdst+b; 2 o=relu(acc+b)*rsrc; 3 o=relu(acc*rdst+b)*rsrc
// BN: 1 = accumulate column sums/sqs of stored bf16 into bnbuf[0..255]
//     2 = (with AMODE=1) derive scale/shift from bnbuf + gamma/beta + invM
template <int AMODE, int EMODE, int OUTBF, int BN>
__global__ __launch_bounds__(256) void gemm_mfma(
    const void* __restrict__ Ain, const short* __restrict__ WT,
    const float* __restrict__ bias,
    const float* __restrict__ aux0, const float* __restrict__ aux1,
    const float* __restrict__ rdst, const float* __restrict__ rsrc,
    void* __restrict__ Cout, int M, float* __restrict__ bnbuf, float invM)
{
    __shared__ __align__(16) short sA[128 * 128];
    __shared__ float sB[2048];               // BN==1 column partials
    const int t    = threadIdx.x;
    const int w    = t >> 6;
    const int lane = t & 63;
    const int ln   = lane & 15;
    const int quad = lane >> 4;
    const int wrow = (w >> 1) * 64;
    const int wcol = (w & 1) * 64;
    const int r0   = blockIdx.x * 128;

    // B fragments from global (L2-resident WT), in flight under A staging
    bh8 breg[4][4];
#pragma unroll
    for (int ks = 0; ks < 4; ++ks)
#pragma unroll
        for (int nt = 0; nt < 4; ++nt) {
            const int n = wcol + nt * 16 + ln;
            breg[ks][nt] = *(const bh8*)(WT + n * D + ks * 32 + quad * 8);
        }

    // ---- stage A tile into swizzled LDS (granule c8 ^= row&7)
    {
        const int rl = t >> 4;
        const int c8 = t & 15;
        float sc[8], sh[8];
        if (AMODE == 1) {
#pragma unroll
            for (int j = 0; j < 8; ++j) {
                if (BN == 2) {
                    const float su = bnbuf[c8 * 8 + j];
                    const float sq = bnbuf[128 + c8 * 8 + j];
                    const float mu = su * invM;
                    const float va = fmaf(-mu, mu, sq * invM);
                    const float rs = rsqrtf(va + 1e-5f);
                    sc[j] = aux0[c8 * 8 + j] * rs;
                    sh[j] = fmaf(-mu, sc[j], aux1[c8 * 8 + j]);
                } else {
                    sc[j] = aux0[c8 * 8 + j];
                    sh[j] = aux1[c8 * 8 + j];
                }
            }
        }
#pragma unroll
        for (int rr = 0; rr < 8; ++rr) {
            const int r_loc = rr * 16 + rl;
            const int row   = min(r0 + r_loc, M - 1);   // clamp: junk rows never stored
            bh8 v;
            if (AMODE == 2) {
                const float4* p = (const float4*)((const float*)Ain +
                                                  (size_t)row * D + c8 * 8);
                float4 x0 = p[0], x1 = p[1];
                v[0] = (short)f2b(x0.x); v[1] = (short)f2b(x0.y);
                v[2] = (short)f2b(x0.z); v[3] = (short)f2b(x0.w);
                v[4] = (short)f2b(x1.x); v[5] = (short)f2b(x1.y);
                v[6] = (short)f2b(x1.z); v[7] = (short)f2b(x1.w);
            } else {
                v = *(const bh8*)((const unsigned short*)Ain +
                                  (size_t)row * D + c8 * 8);
                if (AMODE == 1) {
                    bh8 o;
#pragma unroll
                    for (int j = 0; j < 8; ++j)
                        o[j] = (short)f2b(fmaxf(fmaf(sc[j],
                                    b2f((unsigned short)v[j]), sh[j]), 0.f));
                    v = o;
                }
            }
            *(bh8*)&sA[r_loc * 128 + ((c8 ^ (r_loc & 7)) << 3)] = v;
        }
    }
    __syncthreads();

    // ---- MFMA phase: A from swizzled LDS, B from registers
    f32x4 acc[4][4] = {};
#pragma unroll
    for (int k0 = 0; k0 < 128; k0 += 32) {
        const int ks = k0 >> 5;
        const int g  = (k0 >> 3) + quad;          // 16B granule index
        bh8 a[4];
#pragma unroll
        for (int mt = 0; mt < 4; ++mt) {
            const int r = wrow + mt * 16 + ln;
            a[mt] = *(const bh8*)&sA[r * 128 + ((g ^ (r & 7)) << 3)];
        }
#pragma unroll
        for (int mt = 0; mt < 4; ++mt)
#pragma unroll
            for (int nt = 0; nt < 4; ++nt)
                acc[mt][nt] = __builtin_amdgcn_mfma_f32_16x16x32_bf16(
                    a[mt], breg[ks][nt], acc[mt][nt], 0, 0, 0);
    }

    __syncthreads();   // all sA A-frag reads done before epilogue reuses sA

    // ---- epilogue: C/D layout col = ln, row = quad*4 + reg
    const int widx = ((w >> 1) << 2) + quad;     // 0..7 contributors per column
    float bsum[4] = {0.f, 0.f, 0.f, 0.f};
    float bsq [4] = {0.f, 0.f, 0.f, 0.f};

#pragma unroll
    for (int mt = 0; mt < 4; ++mt) {
        const int rlb = wrow + mt * 16 + quad * 4;   // local row base
        const int rb  = r0 + rlb;
        float rd[4], rs_[4];
        if (EMODE == 1 || EMODE == 3) {
#pragma unroll
            for (int i = 0; i < 4; ++i) rd[i] = (rb + i < M) ? rdst[rb + i] : 0.f;
        }
        if (EMODE == 2 || EMODE == 3) {
#pragma unroll
            for (int i = 0; i < 4; ++i) rs_[i] = (rb + i < M) ? rsrc[rb + i] : 0.f;
        }
#pragma unroll
        for (int nt = 0; nt < 4; ++nt) {
            const int col = wcol + nt * 16 + ln;
            const float bb = bias[col];
#pragma unroll
            for (int i = 0; i < 4; ++i) {
                const int row = rb + i;
                const float v = acc[mt][nt][i];
                float o;
                if (EMODE == 0)      o = v + bb;
                else if (EMODE == 1) o = fmaf(v, rd[i], bb);
                else if (EMODE == 2) o = fmaxf(v + bb, 0.f) * rs_[i];
                else                 o = fmaxf(fmaf(v, rd[i], bb), 0.f) * rs_[i];
                if (OUTBF) {
                    const unsigned short hb = f2b(o);
                    if (BN == 1 && row < M) {
                        const float q = b2f(hb);
                        bsum[nt] += q;
                        bsq[nt]   = fmaf(q, q, bsq[nt]);
                    }
                    const int rl2 = rlb + i;
                    sA[rl2 * 128 + (((col >> 3) ^ (rl2 & 7)) << 3) + (col & 7)] =
                        (short)hb;
                } else if (row < M) {
                    ((float*)Cout)[(size_t)row * D + col] = o;
                }
            }
        }
    }

    if (OUTBF) {
        if (BN == 1) {
#pragma unroll
            for (int nt = 0; nt < 4; ++nt) {
                const int col = wcol + nt * 16 + ln;
                sB[col * 8 + widx]        = bsum[nt];
                sB[1024 + col * 8 + widx] = bsq[nt];
            }
        }
        __syncthreads();
        const int rl = t >> 4, c8 = t & 15;
#pragma unroll
        for (int rr = 0; rr < 8; ++rr) {
            const int r_loc = rr * 16 + rl;
            const int row   = r0 + r_loc;
            if (row < M)
                *(bh8*)((unsigned short*)Cout + (size_t)row * D + c8 * 8) =
                    *(const bh8*)&sA[r_loc * 128 + ((c8 ^ (r_loc & 7)) << 3)];
        }
        if (BN == 1 && t < 128) {
            float s = 0.f, q = 0.f;
#pragma unroll
            for (int j = 0; j < 8; ++j) {
                s += sB[t * 8 + j];
                q += sB[1024 + t * 8 + j];
            }
            unsafeAtomicAdd(&bnbuf[t],       s);
            unsafeAtomicAdd(&bnbuf[128 + t], q);
        }
    }
}

// --------------------------- fused gather + conv GEMM (128-row, R6 best)
// R6 structure (78.5 us) + ONE change: B fragments persistent in registers,
// issued at kernel entry so the 16 L2 loads are in flight beneath the
// entire ~50 us gather phase. R6/R7 showed per-k-step B loads stall the
// MFMA loop (+32 us on pure GEMM; doubled cost on 64-row tiles).
// Occupancy stays grid-limited at 3 blocks/CU (782 blocks / 256 CU);
// launch_bounds(256,3) caps VGPR at 170 (need ~125: breg 64 + gather 48).
template <int EMODE, int OUTBF>
__global__ __launch_bounds__(256, 3) void conv_fused(
    const unsigned short* __restrict__ X, const int* __restrict__ deg,
    const int* __restrict__ csr, const short* __restrict__ WT,
    const float* __restrict__ bias, const float* __restrict__ rdst,
    const float* __restrict__ rsrc, void* __restrict__ Cout, int M)
{
    __shared__ __align__(16) short sA[128 * 128];
    const int t    = threadIdx.x;
    const int w    = t >> 6;
    const int lane = t & 63;
    const int ln   = lane & 15;
    const int quad = lane >> 4;
    const int wrow = (w >> 1) * 64;
    const int wcol = (w & 1) * 64;
    const int r0   = blockIdx.x * 128;

    // B fragments: issue all 16 loads now; latency hides under the gather
    bh8 breg[4][4];
#pragma unroll
    for (int ks = 0; ks < 4; ++ks)
#pragma unroll
        for (int nt = 0; nt < 4; ++nt) {
            const int n = wcol + nt * 16 + ln;
            breg[ks][nt] = *(const bh8*)(WT + n * D + ks * 32 + quad * 8);
        }

    // ---- gather-aggregate 128 dst rows into swizzled sA (8 passes x 16)
    {
        const int nl = t >> 4;
        const int c8 = t & 15;
        for (int p = 0; p < 8; ++p) {
            const int n_loc = p * 16 + nl;
            const int node  = r0 + n_loc;
            float a0[8] = {0.f, 0.f, 0.f, 0.f, 0.f, 0.f, 0.f, 0.f};
            float a1[8] = {0.f, 0.f, 0.f, 0.f, 0.f, 0.f, 0.f, 0.f};
            int cnt = 0;
            const int* row = csr;
            if (node < M) {
                cnt = min(deg[node], CSR_STRIDE);
                row = csr + ((size_t)node << 6);
            }
            int j = 0;
            for (; j + 8 <= cnt; j += 8) {
                int4 s0 = *(const int4*)(row + j);
                int4 s1 = *(const int4*)(row + j + 4);
                bh8 v0 = *(const bh8*)(X + (size_t)s0.x * D + c8 * 8);
                bh8 v1 = *(const bh8*)(X + (size_t)s0.y * D + c8 * 8);
                bh8 v2 = *(const bh8*)(X + (size_t)s0.z * D + c8 * 8);
                bh8 v3 = *(const bh8*)(X + (size_t)s0.w * D + c8 * 8);
                bh8 v4 = *(const bh8*)(X + (size_t)s1.x * D + c8 * 8);
                bh8 v5 = *(const bh8*)(X + (size_t)s1.y * D + c8 * 8);
                bh8 v6 = *(const bh8*)(X + (size_t)s1.z * D + c8 * 8);
                bh8 v7 = *(const bh8*)(X + (size_t)s1.w * D + c8 * 8);
#pragma unroll
                for (int q = 0; q < 8; ++q) {
                    a0[q] += b2f((unsigned short)v0[q]) + b2f((unsigned short)v2[q])
                           + b2f((unsigned short)v4[q]) + b2f((unsigned short)v6[q]);
                    a1[q] += b2f((unsigned short)v1[q]) + b2f((unsigned short)v3[q])
                           + b2f((unsigned short)v5[q]) + b2f((unsigned short)v7[q]);
                }
            }
            for (; j + 4 <= cnt; j += 4) {
                int4 ss = *(const int4*)(row + j);
                bh8 v0 = *(const bh8*)(X + (size_t)ss.x * D + c8 * 8);
                bh8 v1 = *(const bh8*)(X + (size_t)ss.y * D + c8 * 8);
                bh8 v2 = *(const bh8*)(X + (size_t)ss.z * D + c8 * 8);
                bh8 v3 = *(const bh8*)(X + (size_t)ss.w * D + c8 * 8);
#pragma unroll
                for (int q = 0; q < 8; ++q) {
                    a0[q] += b2f((unsigned short)v0[q]) + b2f((unsigned short)v2[q]);
                    a1[q] += b2f((unsigned short)v1[q]) + b2f((unsigned short)v3[q]);
                }
            }
            for (; j < cnt; ++j) {
                bh8 v = *(const bh8*)(X + (size_t)row[j] * D + c8 * 8);
#pragma unroll
                for (int q = 0; q < 8; ++q) a0[q] += b2f((unsigned short)v[q]);
            }
            bh8 o;
#pragma unroll
            for (int q = 0; q < 8; ++q) o[q] = (short)f2b(a0[q] + a1[q]);
            *(bh8*)&sA[n_loc * 128 + ((c8 ^ (n_loc & 7)) << 3)] = o;
        }
    }
    __syncthreads();

    // ---- MFMA: A from swizzled LDS, B from registers
    f32x4 acc[4][4] = {};
#pragma unroll
    for (int k0 = 0; k0 < 128; k0 += 32) {
        const int ks = k0 >> 5;
        const int g  = (k0 >> 3) + quad;
        bh8 a[4];
#pragma unroll
        for (int mt = 0; mt < 4; ++mt) {
            const int r = wrow + mt * 16 + ln;
            a[mt] = *(const bh8*)&sA[r * 128 + ((g ^ (r & 7)) << 3)];
        }
#pragma unroll
        for (int mt = 0; mt < 4; ++mt)
#pragma unroll
            for (int nt = 0; nt < 4; ++nt)
                acc[mt][nt] = __builtin_amdgcn_mfma_f32_16x16x32_bf16(
                    a[mt], breg[ks][nt], acc[mt][nt], 0, 0, 0);
    }

    if (OUTBF) __syncthreads();   // sA reads done before epilogue reuse

    // ---- epilogue: C/D layout col = ln, row = quad*4 + reg
#pragma unroll
    for (int mt = 0; mt < 4; ++mt) {
        const int rlb = wrow + mt * 16 + quad * 4;
        const int rb  = r0 + rlb;
        float rd[4], rs_[4];
        if (EMODE == 1 || EMODE == 3) {
#pragma unroll
            for (int i = 0; i < 4; ++i) rd[i] = (rb + i < M) ? rdst[rb + i] : 0.f;
        }
        if (EMODE == 3) {
#pragma unroll
            for (int i = 0; i < 4; ++i) rs_[i] = (rb + i < M) ? rsrc[rb + i] : 0.f;
        }
#pragma unroll
        for (int nt = 0; nt < 4; ++nt) {
            const int col = wcol + nt * 16 + ln;
            const float bb = bias[col];
#pragma unroll
            for (int i = 0; i < 4; ++i) {
                const int row = rb + i;
                const float v = acc[mt][nt][i];
                float o;
                if (EMODE == 1)      o = fmaf(v, rd[i], bb);
                else if (EMODE == 3) o = fmaxf(fmaf(v, rd[i], bb), 0.f) * rs_[i];
                else                 o = v + bb;
                if (OUTBF) {
                    const int rl2 = rlb + i;
                    sA[rl2 * 128 + (((col >> 3) ^ (rl2 & 7)) << 3) + (col & 7)] =
                        (short)f2b(o);
                } else if (row < M) {
                    ((float*)Cout)[(size_t)row * D + col] = o;
                }
            }
        }
    }

    if (OUTBF) {
        __syncthreads();
        const int rl = t >> 4, c8 = t & 15;
#pragma unroll
        for (int rr = 0; rr < 8; ++rr) {
            const int r_loc = rr * 16 + rl;
            const int row   = r0 + r_loc;
            if (row < M)
                *(bh8*)((unsigned short*)Cout + (size_t)row * D + c8 * 8) =
                    *(const bh8*)&sA[r_loc * 128 + ((c8 ^ (r_loc & 7)) << 3)];
        }
    }
}

// ------------------------------ binned histograms (no global atomics)
// grid (NCH*NR, 2): blockIdx.y picks src/dst. block (c,r): edge chunk c
// vs node range r. Counters 16-bit packed 2-per-int (per-chunk count
// << 64K, no cross-half carry); 6250 ints = 25 KB LDS covers 12500
// nodes -> NR=8: half the edge re-reads of NR=16 at the SAME occupancy.
__global__ __launch_bounds__(256) void edge_hist2(
    const int* __restrict__ src, const int* __restrict__ dst,
    unsigned char* __restrict__ spartial, unsigned char* __restrict__ dpartial,
    int E, int M, int rsize, int csz)
{
    __shared__ int h[6250];   // (rsize+1)/2 <= 6250
    const int t = threadIdx.x;
    const int c = blockIdx.x & (NCH - 1);
    const int r = blockIdx.x >> 6;          // NCH = 64
    const int* __restrict__ idx = blockIdx.y ? dst : src;
    unsigned char* __restrict__ part = blockIdx.y ? dpartial : spartial;
    const int hw = (rsize + 1) >> 1;
    for (int k = t; k < hw; k += 256) h[k] = 0;
    __syncthreads();
    const int lo  = r * rsize;
    const int beg = c * csz;
    const int end = min(E, beg + csz);
    const int4* p4 = (const int4*)idx;
    for (int i = (beg >> 2) + t; i < (end >> 2); i += 256) {
        int4 v = p4[i];
        int a0 = v.x - lo, a1 = v.y - lo, a2 = v.z - lo, a3 = v.w - lo;
        if ((unsigned)a0 < (unsigned)rsize) atomicAdd(&h[a0 >> 1], 1 << ((a0 & 1) * 16));
        if ((unsigned)a1 < (unsigned)rsize) atomicAdd(&h[a1 >> 1], 1 << ((a1 & 1) * 16));
        if ((unsigned)a2 < (unsigned)rsize) atomicAdd(&h[a2 >> 1], 1 << ((a2 & 1) * 16));
        if ((unsigned)a3 < (unsigned)rsize) atomicAdd(&h[a3 >> 1], 1 << ((a3 & 1) * 16));
    }
    for (int i = (end & ~3) + t; i < end; i += 256) {      // tail
        int a = idx[i] - lo;
        if ((unsigned)a < (unsigned)rsize) atomicAdd(&h[a >> 1], 1 << ((a & 1) * 16));
    }
    __syncthreads();
    const int seg = min(rsize, M - lo);
    for (int k = t; k < seg; k += 256) {
        int v = (h[k >> 1] >> ((k & 1) * 16)) & 0xffff;
        part[(size_t)c * M + lo + k] = (unsigned char)v;
    }
}

// -------- scan: per-node chunk prefix (uint8 cursor bases) + degrees/norms
__global__ __launch_bounds__(256) void scan_fin(
    const unsigned char* __restrict__ spartial,
    const unsigned char* __restrict__ dpartial,
    unsigned char* __restrict__ cursor_base, int* __restrict__ dstdeg,
    float* __restrict__ nsrc, float* __restrict__ ndst, int M)
{
    int i = blockIdx.x * 256 + threadIdx.x;
    if (i >= M) return;
    int sd = 0;
#pragma unroll 8
    for (int c = 0; c < NCH; ++c) sd += spartial[(size_t)c * M + i];
    nsrc[i] = rsqrtf(fmaxf((float)sd, 1.f));
    int run = 0;
#pragma unroll 8
    for (int c = 0; c < NCH; ++c) {
        cursor_base[(size_t)c * M + i] = (unsigned char)run;
        run += dpartial[(size_t)c * M + i];
    }
    dstdeg[i] = run;
    ndst[i]   = rsqrtf(fmaxf((float)run, 1.f));
}

// ------------------------- CSR fill: LDS cursors, zero global atomics
// Cursors 16-bit packed 2-per-int (base < 256, per-chunk adds < 256:
// a half never reaches 64K, so atomicAdd halves can't carry across).
__global__ __launch_bounds__(256) void fill_csr(
    const int* __restrict__ src, const int* __restrict__ dst,
    const unsigned char* __restrict__ cursor_base, int* __restrict__ csr,
    int E, int M, int rsize, int csz)
{
    __shared__ int cur[6250];
    const int t  = threadIdx.x;
    const int c  = blockIdx.x & (NCH - 1);
    const int r  = blockIdx.x >> 6;
    const int lo = r * rsize;
    const int seg = min(rsize, M - lo);
    const int hw  = (seg + 1) >> 1;
    for (int k = t; k < hw; k += 256) {
        int k2 = k * 2;
        int v0 = cursor_base[(size_t)c * M + lo + k2];
        int v1 = (k2 + 1 < seg) ? cursor_base[(size_t)c * M + lo + k2 + 1] : 0;
        cur[k] = v0 | (v1 << 16);
    }
    __syncthreads();
    const int beg = c * csz;
    const int end = min(E, beg + csz);
    const int4* s4 = (const int4*)src;
    const int4* d4 = (const int4*)dst;
    for (int i = (beg >> 2) + t; i < (end >> 2); i += 256) {
        int4 dv = d4[i];
        int4 sv = s4[i];
        int a0 = dv.x - lo, a1 = dv.y - lo, a2 = dv.z - lo, a3 = dv.w - lo;
        if ((unsigned)a0 < (unsigned)seg) {
            int pp = atomicAdd(&cur[a0 >> 1], 1 << ((a0 & 1) * 16));
            int p  = (pp >> ((a0 & 1) * 16)) & 0xffff;
            if (p < CSR_STRIDE) csr[((size_t)(lo + a0) << 6) + p] = sv.x;
        }
        if ((unsigned)a1 < (unsigned)seg) {
            int pp = atomicAdd(&cur[a1 >> 1], 1 << ((a1 & 1) * 16));
            int p  = (pp >> ((a1 & 1) * 16)) & 0xffff;
            if (p < CSR_STRIDE) csr[((size_t)(lo + a1) << 6) + p] = sv.y;
        }
        if ((unsigned)a2 < (unsigned)seg) {
            int pp = atomicAdd(&cur[a2 >> 1], 1 << ((a2 & 1) * 16));
            int p  = (pp >> ((a2 & 1) * 16)) & 0xffff;
            if (p < CSR_STRIDE) csr[((size_t)(lo + a2) << 6) + p] = sv.z;
        }
        if ((unsigned)a3 < (unsigned)seg) {
            int pp = atomicAdd(&cur[a3 >> 1], 1 << ((a3 & 1) * 16));
            int p  = (pp >> ((a3 & 1) * 16)) & 0xffff;
            if (p < CSR_STRIDE) csr[((size_t)(lo + a3) << 6) + p] = sv.w;
        }
    }
    for (int i = (end & ~3) + t; i < end; i += 256) {      // tail
        int d = dst[i] - lo;
        if ((unsigned)d < (unsigned)seg) {
            int pp = atomicAdd(&cur[d >> 1], 1 << ((d & 1) * 16));
            int p  = (pp >> ((d & 1) * 16)) & 0xffff;
            if (p < CSR_STRIDE) csr[((size_t)(lo + d) << 6) + p] = src[i];
        }
    }
}

// --------------------------------------------- weight transpose+convert
__global__ __launch_bounds__(256) void wprep(
    const float* __restrict__ W1, const float* __restrict__ W2,
    const float* __restrict__ Wc, short* __restrict__ WT)
{
    const float* W = (blockIdx.y == 0) ? W1 : (blockIdx.y == 1) ? W2 : Wc;
    short* T = WT + (size_t)blockIdx.y * D * D;
    int idx = blockIdx.x * 256 + threadIdx.x;
    int k = idx >> 7, n = idx & 127;
    T[n * D + k] = (short)f2b(W[k * D + n]);
}

// ---------------------------------------------------------------------
extern "C" void kernel_launch(void* const* d_in, const int* in_sizes, int n_in,
                              void* d_out, int out_size, void* d_ws, size_t ws_size,
                              hipStream_t stream)
{
    const float* in_feat = (const float*)d_in[0];
    const int*   src     = (const int*)d_in[1];
    const int*   dst     = (const int*)d_in[2];
    const float* W1      = (const float*)d_in[3];
    const float* b1      = (const float*)d_in[4];
    const float* gamma   = (const float*)d_in[5];
    const float* beta    = (const float*)d_in[6];
    const float* W2      = (const float*)d_in[7];
    const float* b2      = (const float*)d_in[8];
    const float* Wc      = (const float*)d_in[9];
    const float* bc      = (const float*)d_in[10];
    float*       out     = (float*)d_out;

    const int M = in_sizes[0] / D;   // 100000
    const int E = in_sizes[1];       // 1600000

    const int rsize = (M + NR - 1) / NR;             // 12500 (25 KB packed)
    const int csz   = (E + NCH - 1) / NCH;           // 25000
    const int GB    = (M + 127) / 128;               // 782

    // workspace layout
    unsigned short* H1b = (unsigned short*)d_ws;        // M*D bf16: h1 / ping
    unsigned short* Xb  = H1b + (size_t)M * D;          // M*D bf16: X / pong
    // partial tables (uint8, 2*NCH*M = 12.8 MB) alias H1b (dead until gemm1)
    unsigned char* spartial = (unsigned char*)H1b;
    unsigned char* dpartial = spartial + (size_t)NCH * M;
    short* WT      = (short*)(Xb + (size_t)M * D);      // 3*D*D bf16
    int*   dstdeg  = (int*)(WT + 3 * D * D);            // M
    float* bnbuf   = (float*)(dstdeg + M);              // 256: col sums | sqs
    float* nsrc    = bnbuf + 2 * D;                     // M
    float* ndst    = nsrc + M;                          // M
    int*   csr     = (int*)(ndst + M);                  // M * CSR_STRIDE
    unsigned char* cursor_base = (unsigned char*)(csr + (size_t)M * CSR_STRIDE); // NCH*M

    hipMemsetAsync(bnbuf, 0, 2 * D * sizeof(float), stream);

    wprep<<<dim3(64, 3), 256, 0, stream>>>(W1, W2, Wc, WT);

    // graph pipeline (all before the MLP so partials can alias H1b)
    edge_hist2<<<dim3(NCH * NR, 2), 256, 0, stream>>>(src, dst, spartial,
                                                      dpartial, E, M, rsize, csz);
    scan_fin<<<(M + 255) / 256, 256, 0, stream>>>(spartial, dpartial,
                                                  cursor_base, dstdeg,
                                                  nsrc, ndst, M);
    fill_csr<<<NCH * NR, 256, 0, stream>>>(src, dst, cursor_base, csr,
                                           E, M, rsize, csz);

    // MLP: gemm1 accumulates BN stats in its epilogue; gemm2 derives
    // scale/shift from them inline.
    gemm_mfma<2, 0, 1, 1><<<GB, 256, 0, stream>>>(
        in_feat, WT, b1, nullptr, nullptr,
        nullptr, nullptr, H1b, M, bnbuf, 0.f);
    gemm_mfma<1, 2, 1, 2><<<GB, 256, 0, stream>>>(
        H1b, WT + D * D, b2, gamma, beta,
        nullptr, nsrc, Xb, M, bnbuf, 1.f / (float)M);

    // fused gather+conv propagation (128-row tiles): Xb -> H1b -> Xb -> out
    conv_fused<3, 1><<<GB, 256, 0, stream>>>(
        Xb, dstdeg, csr, WT + 2 * D * D, bc, ndst, nsrc, H1b, M);
    conv_fused<3, 1><<<GB, 256, 0, stream>>>(
        H1b, dstdeg, csr, WT + 2 * D * D, bc, ndst, nsrc, Xb, M);
    conv_fused<1, 0><<<GB, 256, 0, stream>>>(
        Xb, dstdeg, csr, WT + 2 * D * D, bc, ndst, nsrc, out, M);
}

// Round 9
// 441.762 us; speedup vs baseline: 1.2049x; 1.2049x over previous
//
#include <hip/hip_runtime.h>

#define D 128
#define CSR_STRIDE 64     // in-deg ~ Poisson(16); P(>64) ~ 0, guarded anyway
#define NCH 64            // edge chunks for binned histogram / fill
#define NR  8             // node ranges: 12500 nodes packed 2-per-int = 25 KB LDS

typedef short bh8 __attribute__((ext_vector_type(8)));
typedef float f32x4 __attribute__((ext_vector_type(4)));

__device__ __forceinline__ unsigned short f2b(float f) {
    unsigned u = __float_as_uint(f);
    u += 0x7fffu + ((u >> 16) & 1u);          // RNE
    return (unsigned short)(u >> 16);
}
__device__ __forceinline__ float b2f(unsigned short h) {
    return __uint_as_float(((unsigned)h) << 16);
}

// ------------------------------------------------------------ MFMA GEMM
// (R5-proven config: ~46 us/dispatch.) C = A @ W, 128x128 tile, 4 waves.
// A staged via 32 KB swizzled LDS; B fragments PERSISTENT in registers.
// NOTE measured matrix (do not revisit):
//   pure GEMM + persistent breg = 46 us ; + per-k-step B = 78 us
//   fused gather + per-k-step B = 78 us ; + persistent breg = 113 us
//     (holding 64 VGPR through the gather serializes its load batches:
//      VGPR 60->84, gather BW 2.97->2.05 TB/s — MLP-limited, R8)
// AMODE: 0 bf16 A; 1 bf16 A + relu(scale*a+shift); 2 fp32 A
// EMODE: 0 o=acc+b; 1 o=acc*rdst+b; 2 o=relu(acc+b)*rsrc; 3 o=relu(acc*rdst+b)*rsrc
// BN: 1 = accumulate column sums/sqs of stored bf16 into bnbuf[0..255]
//     2 = (with AMODE=1) derive scale/shift from bnbuf + gamma/beta + invM
template <int AMODE, int EMODE, int OUTBF, int BN>
__global__ __launch_bounds__(256) void gemm_mfma(
    const void* __restrict__ Ain, const short* __restrict__ WT,
    const float* __restrict__ bias,
    const float* __restrict__ aux0, const float* __restrict__ aux1,
    const float* __restrict__ rdst, const float* __restrict__ rsrc,
    void* __restrict__ Cout, int M, float* __restrict__ bnbuf, float invM)
{
    __shared__ __align__(16) short sA[128 * 128];
    __shared__ float sB[2048];               // BN==1 column partials
    const int t    = threadIdx.x;
    const int w    = t >> 6;
    const int lane = t & 63;
    const int ln   = lane & 15;
    const int quad = lane >> 4;
    const int wrow = (w >> 1) * 64;
    const int wcol = (w & 1) * 64;
    const int r0   = blockIdx.x * 128;

    // B fragments from global (L2-resident WT), in flight under A staging
    bh8 breg[4][4];
#pragma unroll
    for (int ks = 0; ks < 4; ++ks)
#pragma unroll
        for (int nt = 0; nt < 4; ++nt) {
            const int n = wcol + nt * 16 + ln;
            breg[ks][nt] = *(const bh8*)(WT + n * D + ks * 32 + quad * 8);
        }

    // ---- stage A tile into swizzled LDS (granule c8 ^= row&7)
    {
        const int rl = t >> 4;
        const int c8 = t & 15;
        float sc[8], sh[8];
        if (AMODE == 1) {
#pragma unroll
            for (int j = 0; j < 8; ++j) {
                if (BN == 2) {
                    const float su = bnbuf[c8 * 8 + j];
                    const float sq = bnbuf[128 + c8 * 8 + j];
                    const float mu = su * invM;
                    const float va = fmaf(-mu, mu, sq * invM);
                    const float rs = rsqrtf(va + 1e-5f);
                    sc[j] = aux0[c8 * 8 + j] * rs;
                    sh[j] = fmaf(-mu, sc[j], aux1[c8 * 8 + j]);
                } else {
                    sc[j] = aux0[c8 * 8 + j];
                    sh[j] = aux1[c8 * 8 + j];
                }
            }
        }
#pragma unroll
        for (int rr = 0; rr < 8; ++rr) {
            const int r_loc = rr * 16 + rl;
            const int row   = min(r0 + r_loc, M - 1);   // clamp: junk rows never stored
            bh8 v;
            if (AMODE == 2) {
                const float4* p = (const float4*)((const float*)Ain +
                                                  (size_t)row * D + c8 * 8);
                float4 x0 = p[0], x1 = p[1];
                v[0] = (short)f2b(x0.x); v[1] = (short)f2b(x0.y);
                v[2] = (short)f2b(x0.z); v[3] = (short)f2b(x0.w);
                v[4] = (short)f2b(x1.x); v[5] = (short)f2b(x1.y);
                v[6] = (short)f2b(x1.z); v[7] = (short)f2b(x1.w);
            } else {
                v = *(const bh8*)((const unsigned short*)Ain +
                                  (size_t)row * D + c8 * 8);
                if (AMODE == 1) {
                    bh8 o;
#pragma unroll
                    for (int j = 0; j < 8; ++j)
                        o[j] = (short)f2b(fmaxf(fmaf(sc[j],
                                    b2f((unsigned short)v[j]), sh[j]), 0.f));
                    v = o;
                }
            }
            *(bh8*)&sA[r_loc * 128 + ((c8 ^ (r_loc & 7)) << 3)] = v;
        }
    }
    __syncthreads();

    // ---- MFMA phase: A from swizzled LDS, B from registers
    f32x4 acc[4][4] = {};
#pragma unroll
    for (int k0 = 0; k0 < 128; k0 += 32) {
        const int ks = k0 >> 5;
        const int g  = (k0 >> 3) + quad;          // 16B granule index
        bh8 a[4];
#pragma unroll
        for (int mt = 0; mt < 4; ++mt) {
            const int r = wrow + mt * 16 + ln;
            a[mt] = *(const bh8*)&sA[r * 128 + ((g ^ (r & 7)) << 3)];
        }
#pragma unroll
        for (int mt = 0; mt < 4; ++mt)
#pragma unroll
            for (int nt = 0; nt < 4; ++nt)
                acc[mt][nt] = __builtin_amdgcn_mfma_f32_16x16x32_bf16(
                    a[mt], breg[ks][nt], acc[mt][nt], 0, 0, 0);
    }

    __syncthreads();   // all sA A-frag reads done before epilogue reuses sA

    // ---- epilogue: C/D layout col = ln, row = quad*4 + reg
    const int widx = ((w >> 1) << 2) + quad;     // 0..7 contributors per column
    float bsum[4] = {0.f, 0.f, 0.f, 0.f};
    float bsq [4] = {0.f, 0.f, 0.f, 0.f};

#pragma unroll
    for (int mt = 0; mt < 4; ++mt) {
        const int rlb = wrow + mt * 16 + quad * 4;   // local row base
        const int rb  = r0 + rlb;
        float rd[4], rs_[4];
        if (EMODE == 1 || EMODE == 3) {
#pragma unroll
            for (int i = 0; i < 4; ++i) rd[i] = (rb + i < M) ? rdst[rb + i] : 0.f;
        }
        if (EMODE == 2 || EMODE == 3) {
#pragma unroll
            for (int i = 0; i < 4; ++i) rs_[i] = (rb + i < M) ? rsrc[rb + i] : 0.f;
        }
#pragma unroll
        for (int nt = 0; nt < 4; ++nt) {
            const int col = wcol + nt * 16 + ln;
            const float bb = bias[col];
#pragma unroll
            for (int i = 0; i < 4; ++i) {
                const int row = rb + i;
                const float v = acc[mt][nt][i];
                float o;
                if (EMODE == 0)      o = v + bb;
                else if (EMODE == 1) o = fmaf(v, rd[i], bb);
                else if (EMODE == 2) o = fmaxf(v + bb, 0.f) * rs_[i];
                else                 o = fmaxf(fmaf(v, rd[i], bb), 0.f) * rs_[i];
                if (OUTBF) {
                    const unsigned short hb = f2b(o);
                    if (BN == 1 && row < M) {
                        const float q = b2f(hb);
                        bsum[nt] += q;
                        bsq[nt]   = fmaf(q, q, bsq[nt]);
                    }
                    const int rl2 = rlb + i;
                    sA[rl2 * 128 + (((col >> 3) ^ (rl2 & 7)) << 3) + (col & 7)] =
                        (short)hb;
                } else if (row < M) {
                    ((float*)Cout)[(size_t)row * D + col] = o;
                }
            }
        }
    }

    if (OUTBF) {
        if (BN == 1) {
#pragma unroll
            for (int nt = 0; nt < 4; ++nt) {
                const int col = wcol + nt * 16 + ln;
                sB[col * 8 + widx]        = bsum[nt];
                sB[1024 + col * 8 + widx] = bsq[nt];
            }
        }
        __syncthreads();
        const int rl = t >> 4, c8 = t & 15;
#pragma unroll
        for (int rr = 0; rr < 8; ++rr) {
            const int r_loc = rr * 16 + rl;
            const int row   = r0 + r_loc;
            if (row < M)
                *(bh8*)((unsigned short*)Cout + (size_t)row * D + c8 * 8) =
                    *(const bh8*)&sA[r_loc * 128 + ((c8 ^ (r_loc & 7)) << 3)];
        }
        if (BN == 1 && t < 128) {
            float s = 0.f, q = 0.f;
#pragma unroll
            for (int j = 0; j < 8; ++j) {
                s += sB[t * 8 + j];
                q += sB[1024 + t * 8 + j];
            }
            unsafeAtomicAdd(&bnbuf[t],       s);
            unsafeAtomicAdd(&bnbuf[128 + t], q);
        }
    }
}

// --------------------------- fused gather + conv GEMM (R6-proven: 78.5 us)
// 128-row tile, B loaded per k-step (transient registers). Do NOT hold
// persistent breg here: R8 measured 113 us — the 64 live VGPRs serialize
// the gather's 8-wide load batches (MLP-limited, BW 2.97 -> 2.05 TB/s).
// Gather mapping/sum order bit-identical to the original agg_gather.
template <int EMODE, int OUTBF>
__global__ __launch_bounds__(256, 3) void conv_fused(
    const unsigned short* __restrict__ X, const int* __restrict__ deg,
    const int* __restrict__ csr, const short* __restrict__ WT,
    const float* __restrict__ bias, const float* __restrict__ rdst,
    const float* __restrict__ rsrc, void* __restrict__ Cout, int M)
{
    __shared__ __align__(16) short sA[128 * 128];
    const int t    = threadIdx.x;
    const int w    = t >> 6;
    const int lane = t & 63;
    const int ln   = lane & 15;
    const int quad = lane >> 4;
    const int wrow = (w >> 1) * 64;
    const int wcol = (w & 1) * 64;
    const int r0   = blockIdx.x * 128;

    // ---- gather-aggregate 128 dst rows into swizzled sA (8 passes x 16)
    {
        const int nl = t >> 4;
        const int c8 = t & 15;
        for (int p = 0; p < 8; ++p) {
            const int n_loc = p * 16 + nl;
            const int node  = r0 + n_loc;
            float a0[8] = {0.f, 0.f, 0.f, 0.f, 0.f, 0.f, 0.f, 0.f};
            float a1[8] = {0.f, 0.f, 0.f, 0.f, 0.f, 0.f, 0.f, 0.f};
            int cnt = 0;
            const int* row = csr;
            if (node < M) {
                cnt = min(deg[node], CSR_STRIDE);
                row = csr + ((size_t)node << 6);
            }
            int j = 0;
            for (; j + 8 <= cnt; j += 8) {
                int4 s0 = *(const int4*)(row + j);
                int4 s1 = *(const int4*)(row + j + 4);
                bh8 v0 = *(const bh8*)(X + (size_t)s0.x * D + c8 * 8);
                bh8 v1 = *(const bh8*)(X + (size_t)s0.y * D + c8 * 8);
                bh8 v2 = *(const bh8*)(X + (size_t)s0.z * D + c8 * 8);
                bh8 v3 = *(const bh8*)(X + (size_t)s0.w * D + c8 * 8);
                bh8 v4 = *(const bh8*)(X + (size_t)s1.x * D + c8 * 8);
                bh8 v5 = *(const bh8*)(X + (size_t)s1.y * D + c8 * 8);
                bh8 v6 = *(const bh8*)(X + (size_t)s1.z * D + c8 * 8);
                bh8 v7 = *(const bh8*)(X + (size_t)s1.w * D + c8 * 8);
#pragma unroll
                for (int q = 0; q < 8; ++q) {
                    a0[q] += b2f((unsigned short)v0[q]) + b2f((unsigned short)v2[q])
                           + b2f((unsigned short)v4[q]) + b2f((unsigned short)v6[q]);
                    a1[q] += b2f((unsigned short)v1[q]) + b2f((unsigned short)v3[q])
                           + b2f((unsigned short)v5[q]) + b2f((unsigned short)v7[q]);
                }
            }
            for (; j + 4 <= cnt; j += 4) {
                int4 ss = *(const int4*)(row + j);
                bh8 v0 = *(const bh8*)(X + (size_t)ss.x * D + c8 * 8);
                bh8 v1 = *(const bh8*)(X + (size_t)ss.y * D + c8 * 8);
                bh8 v2 = *(const bh8*)(X + (size_t)ss.z * D + c8 * 8);
                bh8 v3 = *(const bh8*)(X + (size_t)ss.w * D + c8 * 8);
#pragma unroll
                for (int q = 0; q < 8; ++q) {
                    a0[q] += b2f((unsigned short)v0[q]) + b2f((unsigned short)v2[q]);
                    a1[q] += b2f((unsigned short)v1[q]) + b2f((unsigned short)v3[q]);
                }
            }
            for (; j < cnt; ++j) {
                bh8 v = *(const bh8*)(X + (size_t)row[j] * D + c8 * 8);
#pragma unroll
                for (int q = 0; q < 8; ++q) a0[q] += b2f((unsigned short)v[q]);
            }
            bh8 o;
#pragma unroll
            for (int q = 0; q < 8; ++q) o[q] = (short)f2b(a0[q] + a1[q]);
            *(bh8*)&sA[n_loc * 128 + ((c8 ^ (n_loc & 7)) << 3)] = o;
        }
    }
    __syncthreads();

    // ---- MFMA: A from swizzled LDS, B per k-step from L2-resident WT
    f32x4 acc[4][4] = {};
#pragma unroll
    for (int k0 = 0; k0 < 128; k0 += 32) {
        const int ks = k0 >> 5;
        const int g  = (k0 >> 3) + quad;
        bh8 a[4], b[4];
#pragma unroll
        for (int nt = 0; nt < 4; ++nt) {
            const int n = wcol + nt * 16 + ln;
            b[nt] = *(const bh8*)(WT + n * D + ks * 32 + quad * 8);
        }
#pragma unroll
        for (int mt = 0; mt < 4; ++mt) {
            const int r = wrow + mt * 16 + ln;
            a[mt] = *(const bh8*)&sA[r * 128 + ((g ^ (r & 7)) << 3)];
        }
#pragma unroll
        for (int mt = 0; mt < 4; ++mt)
#pragma unroll
            for (int nt = 0; nt < 4; ++nt)
                acc[mt][nt] = __builtin_amdgcn_mfma_f32_16x16x32_bf16(
                    a[mt], b[nt], acc[mt][nt], 0, 0, 0);
    }

    if (OUTBF) __syncthreads();   // sA reads done before epilogue reuse

    // ---- epilogue: C/D layout col = ln, row = quad*4 + reg
#pragma unroll
    for (int mt = 0; mt < 4; ++mt) {
        const int rlb = wrow + mt * 16 + quad * 4;
        const int rb  = r0 + rlb;
        float rd[4], rs_[4];
        if (EMODE == 1 || EMODE == 3) {
#pragma unroll
            for (int i = 0; i < 4; ++i) rd[i] = (rb + i < M) ? rdst[rb + i] : 0.f;
        }
        if (EMODE == 3) {
#pragma unroll
            for (int i = 0; i < 4; ++i) rs_[i] = (rb + i < M) ? rsrc[rb + i] : 0.f;
        }
#pragma unroll
        for (int nt = 0; nt < 4; ++nt) {
            const int col = wcol + nt * 16 + ln;
            const float bb = bias[col];
#pragma unroll
            for (int i = 0; i < 4; ++i) {
                const int row = rb + i;
                const float v = acc[mt][nt][i];
                float o;
                if (EMODE == 1)      o = fmaf(v, rd[i], bb);
                else if (EMODE == 3) o = fmaxf(fmaf(v, rd[i], bb), 0.f) * rs_[i];
                else                 o = v + bb;
                if (OUTBF) {
                    const int rl2 = rlb + i;
                    sA[rl2 * 128 + (((col >> 3) ^ (rl2 & 7)) << 3) + (col & 7)] =
                        (short)f2b(o);
                } else if (row < M) {
                    ((float*)Cout)[(size_t)row * D + col] = o;
                }
            }
        }
    }

    if (OUTBF) {
        __syncthreads();
        const int rl = t >> 4, c8 = t & 15;
#pragma unroll
        for (int rr = 0; rr < 8; ++rr) {
            const int r_loc = rr * 16 + rl;
            const int row   = r0 + r_loc;
            if (row < M)
                *(bh8*)((unsigned short*)Cout + (size_t)row * D + c8 * 8) =
                    *(const bh8*)&sA[r_loc * 128 + ((c8 ^ (r_loc & 7)) << 3)];
        }
    }
}

// ------------------------------ binned histograms (no global atomics)
// grid (NCH*NR, 2): blockIdx.y picks src/dst. block (c,r): edge chunk c
// vs node range r. Counters 16-bit packed 2-per-int (per-chunk count
// << 64K, no cross-half carry); 6250 ints = 25 KB LDS covers 12500
// nodes -> NR=8: half the edge re-reads of NR=16 at the SAME occupancy.
__global__ __launch_bounds__(256) void edge_hist2(
    const int* __restrict__ src, const int* __restrict__ dst,
    unsigned char* __restrict__ spartial, unsigned char* __restrict__ dpartial,
    int E, int M, int rsize, int csz)
{
    __shared__ int h[6250];   // (rsize+1)/2 <= 6250
    const int t = threadIdx.x;
    const int c = blockIdx.x & (NCH - 1);
    const int r = blockIdx.x >> 6;          // NCH = 64
    const int* __restrict__ idx = blockIdx.y ? dst : src;
    unsigned char* __restrict__ part = blockIdx.y ? dpartial : spartial;
    const int hw = (rsize + 1) >> 1;
    for (int k = t; k < hw; k += 256) h[k] = 0;
    __syncthreads();
    const int lo  = r * rsize;
    const int beg = c * csz;
    const int end = min(E, beg + csz);
    const int4* p4 = (const int4*)idx;
    for (int i = (beg >> 2) + t; i < (end >> 2); i += 256) {
        int4 v = p4[i];
        int a0 = v.x - lo, a1 = v.y - lo, a2 = v.z - lo, a3 = v.w - lo;
        if ((unsigned)a0 < (unsigned)rsize) atomicAdd(&h[a0 >> 1], 1 << ((a0 & 1) * 16));
        if ((unsigned)a1 < (unsigned)rsize) atomicAdd(&h[a1 >> 1], 1 << ((a1 & 1) * 16));
        if ((unsigned)a2 < (unsigned)rsize) atomicAdd(&h[a2 >> 1], 1 << ((a2 & 1) * 16));
        if ((unsigned)a3 < (unsigned)rsize) atomicAdd(&h[a3 >> 1], 1 << ((a3 & 1) * 16));
    }
    for (int i = (end & ~3) + t; i < end; i += 256) {      // tail
        int a = idx[i] - lo;
        if ((unsigned)a < (unsigned)rsize) atomicAdd(&h[a >> 1], 1 << ((a & 1) * 16));
    }
    __syncthreads();
    const int seg = min(rsize, M - lo);
    for (int k = t; k < seg; k += 256) {
        int v = (h[k >> 1] >> ((k & 1) * 16)) & 0xffff;
        part[(size_t)c * M + lo + k] = (unsigned char)v;
    }
}

// -------- scan: per-node chunk prefix (uint8 cursor bases) + degrees/norms
__global__ __launch_bounds__(256) void scan_fin(
    const unsigned char* __restrict__ spartial,
    const unsigned char* __restrict__ dpartial,
    unsigned char* __restrict__ cursor_base, int* __restrict__ dstdeg,
    float* __restrict__ nsrc, float* __restrict__ ndst, int M)
{
    int i = blockIdx.x * 256 + threadIdx.x;
    if (i >= M) return;
    int sd = 0;
#pragma unroll 8
    for (int c = 0; c < NCH; ++c) sd += spartial[(size_t)c * M + i];
    nsrc[i] = rsqrtf(fmaxf((float)sd, 1.f));
    int run = 0;
#pragma unroll 8
    for (int c = 0; c < NCH; ++c) {
        cursor_base[(size_t)c * M + i] = (unsigned char)run;
        run += dpartial[(size_t)c * M + i];
    }
    dstdeg[i] = run;
    ndst[i]   = rsqrtf(fmaxf((float)run, 1.f));
}

// ------------------------- CSR fill: LDS cursors, zero global atomics
// Cursors 16-bit packed 2-per-int (base < 256, per-chunk adds < 256:
// a half never reaches 64K, so atomicAdd halves can't carry across).
__global__ __launch_bounds__(256) void fill_csr(
    const int* __restrict__ src, const int* __restrict__ dst,
    const unsigned char* __restrict__ cursor_base, int* __restrict__ csr,
    int E, int M, int rsize, int csz)
{
    __shared__ int cur[6250];
    const int t  = threadIdx.x;
    const int c  = blockIdx.x & (NCH - 1);
    const int r  = blockIdx.x >> 6;
    const int lo = r * rsize;
    const int seg = min(rsize, M - lo);
    const int hw  = (seg + 1) >> 1;
    for (int k = t; k < hw; k += 256) {
        int k2 = k * 2;
        int v0 = cursor_base[(size_t)c * M + lo + k2];
        int v1 = (k2 + 1 < seg) ? cursor_base[(size_t)c * M + lo + k2 + 1] : 0;
        cur[k] = v0 | (v1 << 16);
    }
    __syncthreads();
    const int beg = c * csz;
    const int end = min(E, beg + csz);
    const int4* s4 = (const int4*)src;
    const int4* d4 = (const int4*)dst;
    for (int i = (beg >> 2) + t; i < (end >> 2); i += 256) {
        int4 dv = d4[i];
        int4 sv = s4[i];
        int a0 = dv.x - lo, a1 = dv.y - lo, a2 = dv.z - lo, a3 = dv.w - lo;
        if ((unsigned)a0 < (unsigned)seg) {
            int pp = atomicAdd(&cur[a0 >> 1], 1 << ((a0 & 1) * 16));
            int p  = (pp >> ((a0 & 1) * 16)) & 0xffff;
            if (p < CSR_STRIDE) csr[((size_t)(lo + a0) << 6) + p] = sv.x;
        }
        if ((unsigned)a1 < (unsigned)seg) {
            int pp = atomicAdd(&cur[a1 >> 1], 1 << ((a1 & 1) * 16));
            int p  = (pp >> ((a1 & 1) * 16)) & 0xffff;
            if (p < CSR_STRIDE) csr[((size_t)(lo + a1) << 6) + p] = sv.y;
        }
        if ((unsigned)a2 < (unsigned)seg) {
            int pp = atomicAdd(&cur[a2 >> 1], 1 << ((a2 & 1) * 16));
            int p  = (pp >> ((a2 & 1) * 16)) & 0xffff;
            if (p < CSR_STRIDE) csr[((size_t)(lo + a2) << 6) + p] = sv.z;
        }
        if ((unsigned)a3 < (unsigned)seg) {
            int pp = atomicAdd(&cur[a3 >> 1], 1 << ((a3 & 1) * 16));
            int p  = (pp >> ((a3 & 1) * 16)) & 0xffff;
            if (p < CSR_STRIDE) csr[((size_t)(lo + a3) << 6) + p] = sv.w;
        }
    }
    for (int i = (end & ~3) + t; i < end; i += 256) {      // tail
        int d = dst[i] - lo;
        if ((unsigned)d < (unsigned)seg) {
            int pp = atomicAdd(&cur[d >> 1], 1 << ((d & 1) * 16));
            int p  = (pp >> ((d & 1) * 16)) & 0xffff;
            if (p < CSR_STRIDE) csr[((size_t)(lo + d) << 6) + p] = src[i];
        }
    }
}

// --------------------------------------------- weight transpose+convert
__global__ __launch_bounds__(256) void wprep(
    const float* __restrict__ W1, const float* __restrict__ W2,
    const float* __restrict__ Wc, short* __restrict__ WT)
{
    const float* W = (blockIdx.y == 0) ? W1 : (blockIdx.y == 1) ? W2 : Wc;
    short* T = WT + (size_t)blockIdx.y * D * D;
    int idx = blockIdx.x * 256 + threadIdx.x;
    int k = idx >> 7, n = idx & 127;
    T[n * D + k] = (short)f2b(W[k * D + n]);
}

// ---------------------------------------------------------------------
extern "C" void kernel_launch(void* const* d_in, const int* in_sizes, int n_in,
                              void* d_out, int out_size, void* d_ws, size_t ws_size,
                              hipStream_t stream)
{
    const float* in_feat = (const float*)d_in[0];
    const int*   src     = (const int*)d_in[1];
    const int*   dst     = (const int*)d_in[2];
    const float* W1      = (const float*)d_in[3];
    const float* b1      = (const float*)d_in[4];
    const float* gamma   = (const float*)d_in[5];
    const float* beta    = (const float*)d_in[6];
    const float* W2      = (const float*)d_in[7];
    const float* b2      = (const float*)d_in[8];
    const float* Wc      = (const float*)d_in[9];
    const float* bc      = (const float*)d_in[10];
    float*       out     = (float*)d_out;

    const int M = in_sizes[0] / D;   // 100000
    const int E = in_sizes[1];       // 1600000

    const int rsize = (M + NR - 1) / NR;             // 12500 (25 KB packed)
    const int csz   = (E + NCH - 1) / NCH;           // 25000
    const int GB    = (M + 127) / 128;               // 782

    // workspace layout
    unsigned short* H1b = (unsigned short*)d_ws;        // M*D bf16: h1 / ping
    unsigned short* Xb  = H1b + (size_t)M * D;          // M*D bf16: X / pong
    // partial tables (uint8, 2*NCH*M = 12.8 MB) alias H1b (dead until gemm1)
    unsigned char* spartial = (unsigned char*)H1b;
    unsigned char* dpartial = spartial + (size_t)NCH * M;
    short* WT      = (short*)(Xb + (size_t)M * D);      // 3*D*D bf16
    int*   dstdeg  = (int*)(WT + 3 * D * D);            // M
    float* bnbuf   = (float*)(dstdeg + M);              // 256: col sums | sqs
    float* nsrc    = bnbuf + 2 * D;                     // M
    float* ndst    = nsrc + M;                          // M
    int*   csr     = (int*)(ndst + M);                  // M * CSR_STRIDE
    unsigned char* cursor_base = (unsigned char*)(csr + (size_t)M * CSR_STRIDE); // NCH*M

    hipMemsetAsync(bnbuf, 0, 2 * D * sizeof(float), stream);

    wprep<<<dim3(64, 3), 256, 0, stream>>>(W1, W2, Wc, WT);

    // graph pipeline (all before the MLP so partials can alias H1b)
    edge_hist2<<<dim3(NCH * NR, 2), 256, 0, stream>>>(src, dst, spartial,
                                                      dpartial, E, M, rsize, csz);
    scan_fin<<<(M + 255) / 256, 256, 0, stream>>>(spartial, dpartial,
                                                  cursor_base, dstdeg,
                                                  nsrc, ndst, M);
    fill_csr<<<NCH * NR, 256, 0, stream>>>(src, dst, cursor_base, csr,
                                           E, M, rsize, csz);

    // MLP: gemm1 accumulates BN stats in its epilogue; gemm2 derives
    // scale/shift from them inline.
    gemm_mfma<2, 0, 1, 1><<<GB, 256, 0, stream>>>(
        in_feat, WT, b1, nullptr, nullptr,
        nullptr, nullptr, H1b, M, bnbuf, 0.f);
    gemm_mfma<1, 2, 1, 2><<<GB, 256, 0, stream>>>(
        H1b, WT + D * D, b2, gamma, beta,
        nullptr, nsrc, Xb, M, bnbuf, 1.f / (float)M);

    // fused gather+conv propagation (128-row tiles): Xb -> H1b -> Xb -> out
    conv_fused<3, 1><<<GB, 256, 0, stream>>>(
        Xb, dstdeg, csr, WT + 2 * D * D, bc, ndst, nsrc, H1b, M);
    conv_fused<3, 1><<<GB, 256, 0, stream>>>(
        H1b, dstdeg, csr, WT + 2 * D * D, bc, ndst, nsrc, Xb, M);
    conv_fused<1, 0><<<GB, 256, 0, stream>>>(
        Xb, dstdeg, csr, WT + 2 * D * D, bc, ndst, nsrc, out, M);
}